// Round 1
// baseline (379.351 us; speedup 1.0000x reference)
//
#include <hip/hip_runtime.h>
#include <hip/hip_bf16.h>

#define N_NODES 32768
#define N_EDGES 196608
#define N_GRAPHS 256
#define DEG 6
#define HID 128
#define RVD 16
#define EMB 112
#define VOCAB 128
#define TGT 256
#define DEPTH 5

#define LOG7 1.9459101090932196f
#define ILOG7 0.5138983423697507f

typedef __hip_bfloat16 bf16;
using frag_ab = __attribute__((ext_vector_type(8))) short;   // 8 bf16
using frag_cd = __attribute__((ext_vector_type(4))) float;   // 4 f32

static __device__ __forceinline__ float b2f(bf16 x) { return __bfloat162float(x); }
static __device__ __forceinline__ bf16  f2b(float x) { return __float2bfloat16(x); }
static __device__ __forceinline__ short f2s(float x) {
    bf16 b = __float2bfloat16(x);
    return *reinterpret_cast<short*>(&b);
}
static __device__ __forceinline__ float us2f(unsigned short u) {
    unsigned int x = ((unsigned int)u) << 16;
    return __uint_as_float(x);
}
static __device__ __forceinline__ unsigned short f2us(float x) {
    bf16 b = __float2bfloat16(x);
    return *reinterpret_cast<unsigned short*>(&b);
}

// ---------------- unified prep: encode + packs + bond table, one dispatch ----------------
#define PB_ENC  16384
#define PB_WB   (PB_ENC + 640)
#define PB_WC   (PB_WB + 1600)
#define PB_WR   (PB_WC + 80)
#define PB_CODE (PB_WR + 768)
#define PB_T    (PB_CODE + 320)

__global__ __launch_bounds__(256) void prep_k(const int* __restrict__ af, const float* __restrict__ rx,
                                              const float* __restrict__ aemb, bf16* __restrict__ h,
                                              const float* __restrict__ preW, const float* __restrict__ preB,
                                              const float* __restrict__ postW,
                                              const int* __restrict__ bfeat, const float* __restrict__ bemb,
                                              bf16* __restrict__ wb, bf16* __restrict__ wc,
                                              bf16* __restrict__ wrB, unsigned char* __restrict__ codeA,
                                              bf16* __restrict__ Tb) {
    int blk = blockIdx.x, tid = threadIdx.x;
    if (blk < PB_ENC) {
        int v = blk * 2 + (tid >> 7), c = tid & 127;
        float val;
        if (c < EMB) {
            val = 0.f;
            #pragma unroll
            for (int i = 0; i < 9; ++i) {
                int f = af[v * 9 + i];
                val += aemb[(i * VOCAB + f) * EMB + c];
            }
        } else {
            val = rx[v * RVD + (c - EMB)];
        }
        h[(size_t)v * HID + c] = f2b(val);
    } else if (blk < PB_WB) {
        int idx = (blk - PB_ENC) * 256 + tid;
        if (idx < DEPTH * 32768) {
            int j = idx & 7, L = (idx >> 3) & 63, nt = (idx >> 9) & 15, ks = (idx >> 13) & 3, l = idx >> 15;
            int k = ks * 32 + ((L >> 4) * 8) + j;
            int n = nt * 16 + (L & 15);
            const float* W = preW + (size_t)l * 384 * 128;
            float v = (n < 128) ? W[k * 128 + n] : W[(128 + k) * 128 + (n - 128)];
            wb[idx] = f2b(v);
        }
    } else if (blk < PB_WC) {
        int idx = (blk - PB_WB) * 256 + tid;
        if (idx < DEPTH * 81920) {
            int j = idx & 7, L = (idx >> 3) & 63, nt = (idx >> 9) & 7;
            int t = idx >> 12;
            int ks = t % 20, l = t / 20;
            int k = ks * 32 + ((L >> 4) * 8) + j;
            int n = nt * 16 + (L & 15);
            const float* W = postW + (size_t)l * 1664 * 128;
            float v;
            if (k < 128) {
                v = W[k * 128 + n];
            } else {
                int jj = k - 128;
                v = W[(128 + jj) * 128 + n] + LOG7 * W[(640 + jj) * 128 + n] + ILOG7 * W[(1152 + jj) * 128 + n];
            }
            wc[idx] = f2b(v);
        }
    } else if (blk < PB_WR) {
        int idx = (blk - PB_WC) * 256 + tid;
        if (idx < DEPTH * 4096) {
            int j = idx & 7, L = (idx >> 3) & 63, nt = (idx >> 9) & 7, l = idx >> 12;
            int k = ((L >> 4) * 8) + j;
            int n = nt * 16 + (L & 15);
            float v = (k < 16) ? preW[(size_t)l * 384 * 128 + (368 + k) * 128 + n] : 0.f;
            wrB[idx] = f2b(v);
        }
    } else if (blk < PB_CODE) {
        int e = (blk - PB_WR) * 256 + tid;
        if (e < N_EDGES)
            codeA[e] = (unsigned char)(bfeat[e * 3] | (bfeat[e * 3 + 1] << 2) | (bfeat[e * 3 + 2] << 4));
    } else {
        if (tid < 128) {
            int t = blk - PB_CODE;
            int l = t >> 6, cd = t & 63, c = tid;
            int f0 = cd & 3, f1 = (cd >> 2) & 3, f2 = cd >> 4;
            const float* W = preW + (size_t)l * 384 * 128 + 256 * 128;
            float acc = preB[l * 128 + c];
            #pragma unroll 4
            for (int k = 0; k < EMB; ++k) {
                float bsk = bemb[(0 * VOCAB + f0) * EMB + k]
                          + bemb[(1 * VOCAB + f1) * EMB + k]
                          + bemb[(2 * VOCAB + f2) * EMB + k];
                acc += bsk * W[k * 128 + c];
            }
            Tb[(size_t)(l * 64 + cd) * 128 + c] = f2b(acc);
        }
    }
}

// ---------------- layer-0 Z12 GEMM: z12 = h @ wb0 ----------------
__global__ __launch_bounds__(256) void gemm_z12(const bf16* __restrict__ A,
                                                const bf16* __restrict__ Bp,
                                                bf16* __restrict__ C) {
    int lane = threadIdx.x & 63;
    int wave = threadIdx.x >> 6;
    int m = lane & 15, quad = lane >> 4;
    int row0 = blockIdx.x * 64 + wave * 16;

    frag_cd acc[16];
    #pragma unroll
    for (int nt = 0; nt < 16; ++nt)
        #pragma unroll
        for (int i = 0; i < 4; ++i) acc[nt][i] = 0.f;

    const frag_ab* Bf = (const frag_ab*)Bp;
    const bf16* arow = A + (size_t)(row0 + m) * 128;
    #pragma unroll
    for (int ks = 0; ks < 4; ++ks) {
        frag_ab a = *(const frag_ab*)(arow + ks * 32 + quad * 8);
        #pragma unroll
        for (int nt = 0; nt < 16; ++nt) {
            frag_ab b = Bf[(ks * 16 + nt) * 64 + lane];
            acc[nt] = __builtin_amdgcn_mfma_f32_16x16x32_bf16(a, b, acc[nt], 0, 0, 0);
        }
    }
    #pragma unroll
    for (int nt = 0; nt < 16; ++nt) {
        int col = nt * 16 + m;
        #pragma unroll
        for (int r = 0; r < 4; ++r) {
            int row = row0 + quad * 4 + r;
            C[(size_t)row * 256 + col] = f2b(acc[nt][r]);
        }
    }
}

// ---------------- fused posttrans + residual + next-layer Z12 ----------------
// 64-row tile, 512 threads / 8 waves: wave = (rt 0..3, nh 0..1). grid = N/64 = 512.
__global__ __launch_bounds__(512) void layer_k(bf16* __restrict__ h,       // bf16 state, in-place
                                               const bf16* __restrict__ aggc,
                                               const bf16* __restrict__ Bp,
                                               const float* __restrict__ bias,
                                               const bf16* __restrict__ Bn,
                                               bf16* __restrict__ z12) {
    __shared__ __align__(16) bf16 newh[64 * 136];   // pad 136: b128-aligned rows
    int lane = threadIdx.x & 63;
    int wave = threadIdx.x >> 6;
    int rt = wave & 3;        // row-tile
    int nh = wave >> 2;       // col-half
    int m = lane & 15, quad = lane >> 4;
    int row0 = blockIdx.x * 64;
    int rowA = row0 + rt * 16 + m;

    frag_cd acc[4];
    #pragma unroll
    for (int nt = 0; nt < 4; ++nt)
        #pragma unroll
        for (int i = 0; i < 4; ++i) acc[nt][i] = 0.f;

    const frag_ab* Bf = (const frag_ab*)Bp;
    const bf16* arow = h + (size_t)rowA * 128;
    #pragma unroll
    for (int ks = 0; ks < 4; ++ks) {
        frag_ab a = *(const frag_ab*)(arow + ks * 32 + quad * 8);
        #pragma unroll
        for (int nt = 0; nt < 4; ++nt) {
            frag_ab b = Bf[(ks * 8 + nh * 4 + nt) * 64 + lane];
            acc[nt] = __builtin_amdgcn_mfma_f32_16x16x32_bf16(a, b, acc[nt], 0, 0, 0);
        }
    }
    const bf16* grow = aggc + (size_t)rowA * 512;
    #pragma unroll
    for (int ks = 0; ks < 16; ++ks) {
        frag_ab a = *(const frag_ab*)(grow + ks * 32 + quad * 8);
        #pragma unroll
        for (int nt = 0; nt < 4; ++nt) {
            frag_ab b = Bf[((4 + ks) * 8 + nh * 4 + nt) * 64 + lane];
            acc[nt] = __builtin_amdgcn_mfma_f32_16x16x32_bf16(a, b, acc[nt], 0, 0, 0);
        }
    }

    __syncthreads();   // all waves done reading h rows before any in-place write

    #pragma unroll
    for (int nt = 0; nt < 4; ++nt) {
        int col = nh * 64 + nt * 16 + m;
        float bs_ = bias[col];
        #pragma unroll
        for (int r = 0; r < 4; ++r) {
            int lr = rt * 16 + quad * 4 + r;
            int row = row0 + lr;
            float nv = acc[nt][r] + bs_ + b2f(h[(size_t)row * HID + col]);
            bf16 bv = f2b(nv);
            h[(size_t)row * HID + col] = bv;
            newh[lr * 136 + col] = bv;
        }
    }

    if (Bn) {
        __syncthreads();
        const frag_ab* Bf2 = (const frag_ab*)Bn;
        frag_cd a2[8];
        #pragma unroll
        for (int nt = 0; nt < 8; ++nt)
            #pragma unroll
            for (int i = 0; i < 4; ++i) a2[nt][i] = 0.f;
        #pragma unroll
        for (int ks = 0; ks < 4; ++ks) {
            frag_ab a = *(const frag_ab*)&newh[(rt * 16 + m) * 136 + ks * 32 + quad * 8];
            #pragma unroll
            for (int nt = 0; nt < 8; ++nt) {
                frag_ab b = Bf2[(ks * 16 + nh * 8 + nt) * 64 + lane];
                a2[nt] = __builtin_amdgcn_mfma_f32_16x16x32_bf16(a, b, a2[nt], 0, 0, 0);
            }
        }
        #pragma unroll
        for (int nt = 0; nt < 8; ++nt) {
            int col = nh * 128 + nt * 16 + m;
            #pragma unroll
            for (int r = 0; r < 4; ++r) {
                int row = row0 + rt * 16 + quad * 4 + r;
                z12[(size_t)row * 256 + col] = f2b(a2[nt][r]);
            }
        }
    }
}

// ---------------- fused edge-transform + aggregation ----------------
// XCD-aware block swizzle: block b = 8t + x runs on XCD x (round-robin assumption);
// it processes sub-block (t&7) of 64-node window w = x + 8*(t>>3), so all 8 producers
// of window w share the XCD of consumer layer_k block w (also dispatched to XCD w%8).
// Pure work->block permutation: numerics identical; worst case (mapping changed) = old speed.
__global__ __launch_bounds__(256) void fused_agg(const bf16* __restrict__ Z12,
                                                 const int* __restrict__ src,
                                                 const unsigned char* __restrict__ code,
                                                 const float* __restrict__ rand_edge,
                                                 const bf16* __restrict__ Tb,
                                                 const bf16* __restrict__ WrB,
                                                 bf16* __restrict__ aggc) {
    __shared__ __align__(16) float rdot[48 * 130];   // 24.4 KB; stride 130 spreads quad rows across banks
    int tid = threadIdx.x;
    int lane = tid & 63, wave = tid >> 6;
    int xb = blockIdx.x & 7, tb = blockIdx.x >> 3;
    int w = xb + 8 * (tb >> 3);
    int bv = w * 64 + (tb & 7) * 8;

    // ---- phase 0: rdot[48,128] = rnd[48,16] @ Wr via MFMA ----
    if (wave < 3) {
        int m = lane & 15, quad = lane >> 4;
        frag_ab a;
        if (quad < 2) {
            const float4* rp = (const float4*)(rand_edge
                + (size_t)(bv * 6 + wave * 16 + m) * 16 + quad * 8);
            float4 A = rp[0], B = rp[1];
            a[0] = f2s(A.x); a[1] = f2s(A.y); a[2] = f2s(A.z); a[3] = f2s(A.w);
            a[4] = f2s(B.x); a[5] = f2s(B.y); a[6] = f2s(B.z); a[7] = f2s(B.w);
        } else {
            #pragma unroll
            for (int j = 0; j < 8; ++j) a[j] = 0;
        }
        const frag_ab* Bf = (const frag_ab*)WrB;
        #pragma unroll
        for (int nt = 0; nt < 8; ++nt) {
            frag_cd acc;
            #pragma unroll
            for (int i = 0; i < 4; ++i) acc[i] = 0.f;
            acc = __builtin_amdgcn_mfma_f32_16x16x32_bf16(a, Bf[nt * 64 + lane], acc, 0, 0, 0);
            #pragma unroll
            for (int r = 0; r < 4; ++r)
                rdot[(wave * 16 + quad * 4 + r) * 130 + nt * 16 + m] = acc[r];
        }
    }
    __syncthreads();

    // ---- phase A: 2 channels per thread, 64 threads per node ----
    const unsigned short* Zu = (const unsigned short*)Z12;
    const unsigned short* Tu = (const unsigned short*)Tb;
    unsigned short* Au = (unsigned short*)aggc;
    int c = lane * 2;          // even channel pair
    int g = wave;              // node group 0..3, 2 nodes each

    #pragma unroll
    for (int i = 0; i < 2; ++i) {
        int nb = g * 2 + i;
        int v = bv + nb;
        ushort2 z2u = *(const ushort2*)(Zu + (size_t)v * 256 + 128 + c);
        float z2a = us2f(z2u.x), z2b = us2f(z2u.y);
        const int2* sp = (const int2*)(src + v * 6);
        int2 s01 = sp[0], s23 = sp[1], s45 = sp[2];
        const unsigned short* cp = (const unsigned short*)(code + v * 6);
        unsigned short c01 = cp[0], c23 = cp[1], c45 = cp[2];
        int svs[6] = { s01.x, s01.y, s23.x, s23.y, s45.x, s45.y };
        int cds[6] = { c01 & 255, c01 >> 8, c23 & 255, c23 >> 8, c45 & 255, c45 >> 8 };
        ushort2 z1u[6], tvu[6];
        #pragma unroll
        for (int j = 0; j < 6; ++j) z1u[j] = *(const ushort2*)(Zu + (size_t)svs[j] * 256 + c);
        #pragma unroll
        for (int j = 0; j < 6; ++j) tvu[j] = *(const ushort2*)(Tu + cds[j] * 128 + c);
        float sa = 0.f, ssa = 0.f, mxa = -1e30f, mna = 1e30f;
        float sb = 0.f, ssb = 0.f, mxb = -1e30f, mnb = 1e30f;
        #pragma unroll
        for (int j = 0; j < 6; ++j) {
            const float2 rd = *(const float2*)(rdot + ((nb * 6 + j) * 130) + c);
            float va = us2f(z1u[j].x) + z2a + us2f(tvu[j].x) + rd.x;
            float vb = us2f(z1u[j].y) + z2b + us2f(tvu[j].y) + rd.y;
            va = fmaxf(va, 0.f);
            vb = fmaxf(vb, 0.f);
            sa += va; ssa += va * va; mxa = fmaxf(mxa, va); mna = fminf(mna, va);
            sb += vb; ssb += vb * vb; mxb = fmaxf(mxb, vb); mnb = fminf(mnb, vb);
        }
        float meana = sa * (1.f / 6.f), meanb = sb * (1.f / 6.f);
        float msqa = ssa * (1.f / 6.f), msqb = ssb * (1.f / 6.f);
        float sda = sqrtf(fmaxf(msqa - meana * meana, 0.f) + 1e-5f);
        float sdb = sqrtf(fmaxf(msqb - meanb * meanb, 0.f) + 1e-5f);
        size_t base = (size_t)v * 512 + c;
        *(ushort2*)(Au + base)       = make_ushort2(f2us(meana), f2us(meanb));
        *(ushort2*)(Au + base + 128) = make_ushort2(f2us(mxa),  f2us(mxb));
        *(ushort2*)(Au + base + 256) = make_ushort2(f2us(mna),  f2us(mnb));
        *(ushort2*)(Au + base + 384) = make_ushort2(f2us(sda),  f2us(sdb));
    }
}

// ---------------- readout ----------------
__global__ __launch_bounds__(128) void readout(const bf16* __restrict__ h, const float* __restrict__ W1,
                                               const float* __restrict__ b1, const float* __restrict__ W2,
                                               const float* __restrict__ b2, float* __restrict__ out) {
    __shared__ float r[384];
    __shared__ float y1[128];
    int g = blockIdx.x, c = threadIdx.x;
    float s = 0.f, mx = -1e30f;
    for (int v = 0; v < 128; ++v) {
        float hv = b2f(h[((size_t)g * 128 + v) * HID + c]);
        s += hv; mx = fmaxf(mx, hv);
    }
    r[c] = s * (1.f / 128.f);
    r[128 + c] = s;
    r[256 + c] = mx;
    __syncthreads();
    float a1 = b1[c];
    for (int k = 0; k < 384; ++k) a1 += r[k] * W1[k * 128 + c];
    y1[c] = fmaxf(a1, 0.f);
    __syncthreads();
    #pragma unroll
    for (int o = 0; o < 2; ++o) {
        int t = c + o * 128;
        float a2 = b2[t];
        for (int k = 0; k < 128; ++k) a2 += y1[k] * W2[k * 256 + t];
        out[(size_t)g * 256 + t] = a2;
    }
}

// ---------------- launch ----------------
extern "C" void kernel_launch(void* const* d_in, const int* in_sizes, int n_in,
                              void* d_out, int out_size, void* d_ws, size_t ws_size,
                              hipStream_t stream) {
    const int*   atom_feats = (const int*)d_in[0];
    const int*   bond_feats = (const int*)d_in[1];
    const int*   src        = (const int*)d_in[2];
    const float* rand_x     = (const float*)d_in[6];
    const float* rand_edge  = (const float*)d_in[7];
    const float* atom_emb   = (const float*)d_in[8];
    const float* bond_emb   = (const float*)d_in[9];
    const float* pre_W      = (const float*)d_in[10];
    const float* pre_b      = (const float*)d_in[11];
    const float* post_W     = (const float*)d_in[12];
    const float* post_b     = (const float*)d_in[13];
    const float* ro_W1      = (const float*)d_in[14];
    const float* ro_b1      = (const float*)d_in[15];
    const float* ro_W2      = (const float*)d_in[16];
    const float* ro_b2      = (const float*)d_in[17];

    char* p = (char*)d_ws;
    auto alloc = [&](size_t bytes) {
        char* r = p;
        p += (bytes + 255) & ~(size_t)255;
        return r;
    };
    bf16*  h    = (bf16*) alloc((size_t)N_NODES * HID * 2);      // 8 MB (bf16 state)
    bf16*  z12  = (bf16*) alloc((size_t)N_NODES * 256 * 2);      // 16 MB
    bf16*  aggc = (bf16*) alloc((size_t)N_NODES * 512 * 2);      // 32 MB
    bf16*  wb   = (bf16*) alloc((size_t)DEPTH * 32768 * 2);
    bf16*  wc   = (bf16*) alloc((size_t)DEPTH * 81920 * 2);
    bf16*  wrB  = (bf16*) alloc((size_t)DEPTH * 4096 * 2);       // 40 KB
    bf16*  Tb   = (bf16*) alloc((size_t)DEPTH * 64 * 128 * 2);   // 80 KB
    unsigned char* code = (unsigned char*)alloc(N_EDGES);        // 192 KB

    // unified prep (encode + all packs + bond table)
    prep_k<<<PB_T, 256, 0, stream>>>(atom_feats, rand_x, atom_emb, h,
                                     pre_W, pre_b, post_W,
                                     bond_feats, bond_emb,
                                     wb, wc, wrB, code, Tb);

    // layer-0 Z12
    gemm_z12<<<N_NODES / 64, 256, 0, stream>>>(h, wb, z12);

    for (int l = 0; l < DEPTH; ++l) {
        fused_agg<<<N_NODES / 8, 256, 0, stream>>>(
            z12, src, code, rand_edge,
            Tb + (size_t)l * 8192,
            wrB + (size_t)l * 4096, aggc);
        const bf16* wbn = (l + 1 < DEPTH) ? (wb + (size_t)(l + 1) * 32768) : nullptr;
        layer_k<<<N_NODES / 64, 512, 0, stream>>>(
            h, aggc, wc + (size_t)l * 81920, post_b + l * HID, wbn, z12);
    }

    readout<<<N_GRAPHS, 128, 0, stream>>>(h, ro_W1, ro_b1, ro_W2, ro_b2, (float*)d_out);
}

// Round 2
// 344.332 us; speedup vs baseline: 1.1017x; 1.1017x over previous
//
#include <hip/hip_runtime.h>
#include <hip/hip_bf16.h>

#define N_NODES 32768
#define N_EDGES 196608
#define N_GRAPHS 256
#define DEG 6
#define HID 128
#define RVD 16
#define EMB 112
#define VOCAB 128
#define TGT 256
#define DEPTH 5

#define LOG7 1.9459101090932196f
#define ILOG7 0.5138983423697507f

typedef __hip_bfloat16 bf16;
using frag_ab = __attribute__((ext_vector_type(8))) short;   // 8 bf16
using frag_cd = __attribute__((ext_vector_type(4))) float;   // 4 f32

static __device__ __forceinline__ float b2f(bf16 x) { return __bfloat162float(x); }
static __device__ __forceinline__ bf16  f2b(float x) { return __float2bfloat16(x); }
static __device__ __forceinline__ short f2s(float x) {
    bf16 b = __float2bfloat16(x);
    return *reinterpret_cast<short*>(&b);
}
static __device__ __forceinline__ float us2f(unsigned short u) {
    unsigned int x = ((unsigned int)u) << 16;
    return __uint_as_float(x);
}
static __device__ __forceinline__ unsigned short f2us(float x) {
    bf16 b = __float2bfloat16(x);
    return *reinterpret_cast<unsigned short*>(&b);
}

// ---------------- unified prep: encode + packs + bond table, one dispatch ----------------
#define PB_ENC  16384
#define PB_WB   (PB_ENC + 640)
#define PB_WC   (PB_WB + 1600)
#define PB_WR   (PB_WC + 80)
#define PB_CODE (PB_WR + 768)
#define PB_T    (PB_CODE + 320)

__global__ __launch_bounds__(256) void prep_k(const int* __restrict__ af, const float* __restrict__ rx,
                                              const float* __restrict__ aemb, bf16* __restrict__ h,
                                              const float* __restrict__ preW, const float* __restrict__ preB,
                                              const float* __restrict__ postW,
                                              const int* __restrict__ bfeat, const float* __restrict__ bemb,
                                              bf16* __restrict__ wb, bf16* __restrict__ wc,
                                              bf16* __restrict__ wrB, unsigned char* __restrict__ codeA,
                                              bf16* __restrict__ Tb) {
    int blk = blockIdx.x, tid = threadIdx.x;
    if (blk < PB_ENC) {
        int v = blk * 2 + (tid >> 7), c = tid & 127;
        float val;
        if (c < EMB) {
            val = 0.f;
            #pragma unroll
            for (int i = 0; i < 9; ++i) {
                int f = af[v * 9 + i];
                val += aemb[(i * VOCAB + f) * EMB + c];
            }
        } else {
            val = rx[v * RVD + (c - EMB)];
        }
        h[(size_t)v * HID + c] = f2b(val);
    } else if (blk < PB_WB) {
        int idx = (blk - PB_ENC) * 256 + tid;
        if (idx < DEPTH * 32768) {
            int j = idx & 7, L = (idx >> 3) & 63, nt = (idx >> 9) & 15, ks = (idx >> 13) & 3, l = idx >> 15;
            int k = ks * 32 + ((L >> 4) * 8) + j;
            int n = nt * 16 + (L & 15);
            const float* W = preW + (size_t)l * 384 * 128;
            float v = (n < 128) ? W[k * 128 + n] : W[(128 + k) * 128 + (n - 128)];
            wb[idx] = f2b(v);
        }
    } else if (blk < PB_WC) {
        int idx = (blk - PB_WB) * 256 + tid;
        if (idx < DEPTH * 81920) {
            int j = idx & 7, L = (idx >> 3) & 63, nt = (idx >> 9) & 7;
            int t = idx >> 12;
            int ks = t % 20, l = t / 20;
            int k = ks * 32 + ((L >> 4) * 8) + j;
            int n = nt * 16 + (L & 15);
            const float* W = postW + (size_t)l * 1664 * 128;
            float v;
            if (k < 128) {
                v = W[k * 128 + n];
            } else {
                int jj = k - 128;
                v = W[(128 + jj) * 128 + n] + LOG7 * W[(640 + jj) * 128 + n] + ILOG7 * W[(1152 + jj) * 128 + n];
            }
            wc[idx] = f2b(v);
        }
    } else if (blk < PB_WR) {
        int idx = (blk - PB_WC) * 256 + tid;
        if (idx < DEPTH * 4096) {
            int j = idx & 7, L = (idx >> 3) & 63, nt = (idx >> 9) & 7, l = idx >> 12;
            int k = ((L >> 4) * 8) + j;
            int n = nt * 16 + (L & 15);
            float v = (k < 16) ? preW[(size_t)l * 384 * 128 + (368 + k) * 128 + n] : 0.f;
            wrB[idx] = f2b(v);
        }
    } else if (blk < PB_CODE) {
        int e = (blk - PB_WR) * 256 + tid;
        if (e < N_EDGES)
            codeA[e] = (unsigned char)(bfeat[e * 3] | (bfeat[e * 3 + 1] << 2) | (bfeat[e * 3 + 2] << 4));
    } else {
        if (tid < 128) {
            int t = blk - PB_CODE;
            int l = t >> 6, cd = t & 63, c = tid;
            int f0 = cd & 3, f1 = (cd >> 2) & 3, f2 = cd >> 4;
            const float* W = preW + (size_t)l * 384 * 128 + 256 * 128;
            float acc = preB[l * 128 + c];
            #pragma unroll 4
            for (int k = 0; k < EMB; ++k) {
                float bsk = bemb[(0 * VOCAB + f0) * EMB + k]
                          + bemb[(1 * VOCAB + f1) * EMB + k]
                          + bemb[(2 * VOCAB + f2) * EMB + k];
                acc += bsk * W[k * 128 + c];
            }
            Tb[(size_t)(l * 64 + cd) * 128 + c] = f2b(acc);
        }
    }
}

// ---------------- layer-0 Z12 GEMM: z12 = h @ wb0 ----------------
__global__ __launch_bounds__(256) void gemm_z12(const bf16* __restrict__ A,
                                                const bf16* __restrict__ Bp,
                                                bf16* __restrict__ C) {
    int lane = threadIdx.x & 63;
    int wave = threadIdx.x >> 6;
    int m = lane & 15, quad = lane >> 4;
    int row0 = blockIdx.x * 64 + wave * 16;

    frag_cd acc[16];
    #pragma unroll
    for (int nt = 0; nt < 16; ++nt)
        #pragma unroll
        for (int i = 0; i < 4; ++i) acc[nt][i] = 0.f;

    const frag_ab* Bf = (const frag_ab*)Bp;
    const bf16* arow = A + (size_t)(row0 + m) * 128;
    #pragma unroll
    for (int ks = 0; ks < 4; ++ks) {
        frag_ab a = *(const frag_ab*)(arow + ks * 32 + quad * 8);
        #pragma unroll
        for (int nt = 0; nt < 16; ++nt) {
            frag_ab b = Bf[(ks * 16 + nt) * 64 + lane];
            acc[nt] = __builtin_amdgcn_mfma_f32_16x16x32_bf16(a, b, acc[nt], 0, 0, 0);
        }
    }
    #pragma unroll
    for (int nt = 0; nt < 16; ++nt) {
        int col = nt * 16 + m;
        #pragma unroll
        for (int r = 0; r < 4; ++r) {
            int row = row0 + quad * 4 + r;
            C[(size_t)row * 256 + col] = f2b(acc[nt][r]);
        }
    }
}

// ---------------- fully fused layer: agg (LDS-resident) + posttrans + residual + next-z12 ----------------
// Block = 64 nodes, 512 threads / 8 waves. grid = N/64 = 512 (2 blocks/CU).
// agg phase: 8 rounds x 8 nodes. rdot (rand_edge @ Wr) via MFMA into bf16 LDS (48x136),
// wave w aggregates node r*8+w (lane = 2 channels), writing the 64x520 bf16 agg LDS tile.
// GEMM phase: identical to old layer_k but agg A-frags come from LDS (no aggc global buffer).
// newh for the next-z12 GEMM aliases the (dead) agg tile after the posttrans MFMA.
// z12 is ping-pong (Zcur read / Znext written) since agg gathers other blocks' z12 rows.
__global__ __launch_bounds__(512, 4) void fused_layer(bf16* __restrict__ h,
                                                      const bf16* __restrict__ Zcur,
                                                      const int* __restrict__ src,
                                                      const unsigned char* __restrict__ code,
                                                      const float* __restrict__ rand_edge,
                                                      const bf16* __restrict__ Tb,
                                                      const bf16* __restrict__ WrB,
                                                      const bf16* __restrict__ Bp,
                                                      const float* __restrict__ bias,
                                                      const bf16* __restrict__ Bn,
                                                      bf16* __restrict__ Znext) {
    __shared__ __align__(16) bf16 agg_lds[64 * 520];   // 66,560 B; stride 520 = bank spread
    __shared__ __align__(16) bf16 rdot[48 * 136];      // 13,056 B; total 79.6 KB -> 2 blocks/CU

    int tid = threadIdx.x;
    int lane = tid & 63, wave = tid >> 6;
    int m = lane & 15, quad = lane >> 4;
    int row0 = blockIdx.x * 64;

    const unsigned short* Zu = (const unsigned short*)Zcur;
    const unsigned short* Tu = (const unsigned short*)Tb;
    const unsigned short* Ru = (const unsigned short*)rdot;
    unsigned short* Ag = (unsigned short*)agg_lds;
    int c = lane * 2;

    for (int r = 0; r < 8; ++r) {
        int bv = row0 + r * 8;
        // ---- rdot[48][128] = rand_edge[bv*6 .. +48][16] @ Wr (waves 0-2) ----
        if (wave < 3) {
            frag_ab a;
            if (quad < 2) {
                const float4* rp = (const float4*)(rand_edge
                    + (size_t)(bv * 6 + wave * 16 + m) * 16 + quad * 8);
                float4 A = rp[0], B = rp[1];
                a[0] = f2s(A.x); a[1] = f2s(A.y); a[2] = f2s(A.z); a[3] = f2s(A.w);
                a[4] = f2s(B.x); a[5] = f2s(B.y); a[6] = f2s(B.z); a[7] = f2s(B.w);
            } else {
                #pragma unroll
                for (int j = 0; j < 8; ++j) a[j] = 0;
            }
            const frag_ab* Bf = (const frag_ab*)WrB;
            #pragma unroll
            for (int nt = 0; nt < 8; ++nt) {
                frag_cd acc;
                #pragma unroll
                for (int i = 0; i < 4; ++i) acc[i] = 0.f;
                acc = __builtin_amdgcn_mfma_f32_16x16x32_bf16(a, Bf[nt * 64 + lane], acc, 0, 0, 0);
                #pragma unroll
                for (int rr = 0; rr < 4; ++rr)
                    rdot[(wave * 16 + quad * 4 + rr) * 136 + nt * 16 + m] = f2b(acc[rr]);
            }
        }
        __syncthreads();
        // ---- wave w aggregates node bv + w; lane covers channels c, c+1 ----
        {
            int nb = wave;
            int v = bv + nb;
            ushort2 z2u = *(const ushort2*)(Zu + (size_t)v * 256 + 128 + c);
            float z2a = us2f(z2u.x), z2b = us2f(z2u.y);
            const int2* sp = (const int2*)(src + v * 6);
            int2 s01 = sp[0], s23 = sp[1], s45 = sp[2];
            const unsigned short* cp = (const unsigned short*)(code + v * 6);
            unsigned short c01 = cp[0], c23 = cp[1], c45 = cp[2];
            int svs[6] = { s01.x, s01.y, s23.x, s23.y, s45.x, s45.y };
            int cds[6] = { c01 & 255, c01 >> 8, c23 & 255, c23 >> 8, c45 & 255, c45 >> 8 };
            ushort2 z1u[6], tvu[6];
            #pragma unroll
            for (int j = 0; j < 6; ++j) z1u[j] = *(const ushort2*)(Zu + (size_t)svs[j] * 256 + c);
            #pragma unroll
            for (int j = 0; j < 6; ++j) tvu[j] = *(const ushort2*)(Tu + cds[j] * 128 + c);
            float sa = 0.f, ssa = 0.f, mxa = -1e30f, mna = 1e30f;
            float sb = 0.f, ssb = 0.f, mxb = -1e30f, mnb = 1e30f;
            #pragma unroll
            for (int j = 0; j < 6; ++j) {
                ushort2 rdu = *(const ushort2*)(Ru + (nb * 6 + j) * 136 + c);
                float va = us2f(z1u[j].x) + z2a + us2f(tvu[j].x) + us2f(rdu.x);
                float vb = us2f(z1u[j].y) + z2b + us2f(tvu[j].y) + us2f(rdu.y);
                va = fmaxf(va, 0.f);
                vb = fmaxf(vb, 0.f);
                sa += va; ssa += va * va; mxa = fmaxf(mxa, va); mna = fminf(mna, va);
                sb += vb; ssb += vb * vb; mxb = fmaxf(mxb, vb); mnb = fminf(mnb, vb);
            }
            float meana = sa * (1.f / 6.f), meanb = sb * (1.f / 6.f);
            float msqa = ssa * (1.f / 6.f), msqb = ssb * (1.f / 6.f);
            float sda = sqrtf(fmaxf(msqa - meana * meana, 0.f) + 1e-5f);
            float sdb = sqrtf(fmaxf(msqb - meanb * meanb, 0.f) + 1e-5f);
            int lrow = r * 8 + nb;
            size_t base = (size_t)lrow * 520 + c;
            *(ushort2*)(Ag + base)       = make_ushort2(f2us(meana), f2us(meanb));
            *(ushort2*)(Ag + base + 128) = make_ushort2(f2us(mxa),  f2us(mxb));
            *(ushort2*)(Ag + base + 256) = make_ushort2(f2us(mna),  f2us(mnb));
            *(ushort2*)(Ag + base + 384) = make_ushort2(f2us(sda),  f2us(sdb));
        }
        __syncthreads();   // before next round overwrites rdot; last round: agg tile complete
    }

    // ---- GEMM phase: posttrans + residual + next-layer Z12 (waves = (rt, nh)) ----
    int rt = wave & 3, nh = wave >> 2;
    int rowA = row0 + rt * 16 + m;

    frag_cd acc[4];
    #pragma unroll
    for (int nt = 0; nt < 4; ++nt)
        #pragma unroll
        for (int i = 0; i < 4; ++i) acc[nt][i] = 0.f;

    const frag_ab* Bf = (const frag_ab*)Bp;
    const bf16* arow = h + (size_t)rowA * 128;
    #pragma unroll
    for (int ks = 0; ks < 4; ++ks) {
        frag_ab a = *(const frag_ab*)(arow + ks * 32 + quad * 8);
        #pragma unroll
        for (int nt = 0; nt < 4; ++nt) {
            frag_ab b = Bf[(ks * 8 + nh * 4 + nt) * 64 + lane];
            acc[nt] = __builtin_amdgcn_mfma_f32_16x16x32_bf16(a, b, acc[nt], 0, 0, 0);
        }
    }
    const bf16* grow = agg_lds + (size_t)(rt * 16 + m) * 520;
    #pragma unroll
    for (int ks = 0; ks < 16; ++ks) {
        frag_ab a = *(const frag_ab*)(grow + ks * 32 + quad * 8);
        #pragma unroll
        for (int nt = 0; nt < 4; ++nt) {
            frag_ab b = Bf[((4 + ks) * 8 + nh * 4 + nt) * 64 + lane];
            acc[nt] = __builtin_amdgcn_mfma_f32_16x16x32_bf16(a, b, acc[nt], 0, 0, 0);
        }
    }

    __syncthreads();   // all waves done reading h rows + agg_lds before writes

    bf16* newh = agg_lds;   // alias: agg tile is dead; stride 136 (b128-aligned rows)
    #pragma unroll
    for (int nt = 0; nt < 4; ++nt) {
        int col = nh * 64 + nt * 16 + m;
        float bs_ = bias[col];
        #pragma unroll
        for (int r2 = 0; r2 < 4; ++r2) {
            int lr = rt * 16 + quad * 4 + r2;
            int row = row0 + lr;
            float nv = acc[nt][r2] + bs_ + b2f(h[(size_t)row * HID + col]);
            bf16 bv2 = f2b(nv);
            h[(size_t)row * HID + col] = bv2;
            newh[lr * 136 + col] = bv2;
        }
    }

    if (Bn) {
        __syncthreads();
        const frag_ab* Bf2 = (const frag_ab*)Bn;
        frag_cd a2[8];
        #pragma unroll
        for (int nt = 0; nt < 8; ++nt)
            #pragma unroll
            for (int i = 0; i < 4; ++i) a2[nt][i] = 0.f;
        #pragma unroll
        for (int ks = 0; ks < 4; ++ks) {
            frag_ab a = *(const frag_ab*)&newh[(rt * 16 + m) * 136 + ks * 32 + quad * 8];
            #pragma unroll
            for (int nt = 0; nt < 8; ++nt) {
                frag_ab b = Bf2[(ks * 16 + nh * 8 + nt) * 64 + lane];
                a2[nt] = __builtin_amdgcn_mfma_f32_16x16x32_bf16(a, b, a2[nt], 0, 0, 0);
            }
        }
        #pragma unroll
        for (int nt = 0; nt < 8; ++nt) {
            int col = nh * 128 + nt * 16 + m;
            #pragma unroll
            for (int r2 = 0; r2 < 4; ++r2) {
                int row = row0 + rt * 16 + quad * 4 + r2;
                Znext[(size_t)row * 256 + col] = f2b(a2[nt][r2]);
            }
        }
    }
}

// ---------------- readout ----------------
__global__ __launch_bounds__(128) void readout(const bf16* __restrict__ h, const float* __restrict__ W1,
                                               const float* __restrict__ b1, const float* __restrict__ W2,
                                               const float* __restrict__ b2, float* __restrict__ out) {
    __shared__ float r[384];
    __shared__ float y1[128];
    int g = blockIdx.x, c = threadIdx.x;
    float s = 0.f, mx = -1e30f;
    for (int v = 0; v < 128; ++v) {
        float hv = b2f(h[((size_t)g * 128 + v) * HID + c]);
        s += hv; mx = fmaxf(mx, hv);
    }
    r[c] = s * (1.f / 128.f);
    r[128 + c] = s;
    r[256 + c] = mx;
    __syncthreads();
    float a1 = b1[c];
    for (int k = 0; k < 384; ++k) a1 += r[k] * W1[k * 128 + c];
    y1[c] = fmaxf(a1, 0.f);
    __syncthreads();
    #pragma unroll
    for (int o = 0; o < 2; ++o) {
        int t = c + o * 128;
        float a2 = b2[t];
        for (int k = 0; k < 128; ++k) a2 += y1[k] * W2[k * 256 + t];
        out[(size_t)g * 256 + t] = a2;
    }
}

// ---------------- launch ----------------
extern "C" void kernel_launch(void* const* d_in, const int* in_sizes, int n_in,
                              void* d_out, int out_size, void* d_ws, size_t ws_size,
                              hipStream_t stream) {
    const int*   atom_feats = (const int*)d_in[0];
    const int*   bond_feats = (const int*)d_in[1];
    const int*   src        = (const int*)d_in[2];
    const float* rand_x     = (const float*)d_in[6];
    const float* rand_edge  = (const float*)d_in[7];
    const float* atom_emb   = (const float*)d_in[8];
    const float* bond_emb   = (const float*)d_in[9];
    const float* pre_W      = (const float*)d_in[10];
    const float* pre_b      = (const float*)d_in[11];
    const float* post_W     = (const float*)d_in[12];
    const float* post_b     = (const float*)d_in[13];
    const float* ro_W1      = (const float*)d_in[14];
    const float* ro_b1      = (const float*)d_in[15];
    const float* ro_W2      = (const float*)d_in[16];
    const float* ro_b2      = (const float*)d_in[17];

    char* p = (char*)d_ws;
    auto alloc = [&](size_t bytes) {
        char* r = p;
        p += (bytes + 255) & ~(size_t)255;
        return r;
    };
    bf16*  h    = (bf16*) alloc((size_t)N_NODES * HID * 2);      // 8 MB (bf16 state)
    bf16*  z12a = (bf16*) alloc((size_t)N_NODES * 256 * 2);      // 16 MB (ping)
    bf16*  z12b = (bf16*) alloc((size_t)N_NODES * 256 * 2);      // 16 MB (pong)
    bf16*  wb   = (bf16*) alloc((size_t)DEPTH * 32768 * 2);
    bf16*  wc   = (bf16*) alloc((size_t)DEPTH * 81920 * 2);
    bf16*  wrB  = (bf16*) alloc((size_t)DEPTH * 4096 * 2);       // 40 KB
    bf16*  Tb   = (bf16*) alloc((size_t)DEPTH * 64 * 128 * 2);   // 80 KB
    unsigned char* code = (unsigned char*)alloc(N_EDGES);        // 192 KB

    // unified prep (encode + all packs + bond table)
    prep_k<<<PB_T, 256, 0, stream>>>(atom_feats, rand_x, atom_emb, h,
                                     pre_W, pre_b, post_W,
                                     bond_feats, bond_emb,
                                     wb, wc, wrB, code, Tb);

    // layer-0 Z12
    gemm_z12<<<N_NODES / 64, 256, 0, stream>>>(h, wb, z12a);

    bf16* zc = z12a;
    bf16* zn = z12b;
    for (int l = 0; l < DEPTH; ++l) {
        const bf16* wbn = (l + 1 < DEPTH) ? (wb + (size_t)(l + 1) * 32768) : nullptr;
        fused_layer<<<N_NODES / 64, 512, 0, stream>>>(
            h, zc, src, code, rand_edge,
            Tb + (size_t)l * 8192,
            wrB + (size_t)l * 4096,
            wc + (size_t)l * 81920,
            post_b + l * HID,
            wbn, zn);
        bf16* t = zc; zc = zn; zn = t;
    }

    readout<<<N_GRAPHS, 128, 0, stream>>>(h, ro_W1, ro_b1, ro_W2, ro_b2, (float*)d_out);
}

// Round 3
// 337.690 us; speedup vs baseline: 1.1234x; 1.0197x over previous
//
#include <hip/hip_runtime.h>
#include <hip/hip_bf16.h>

#define N_NODES 32768
#define N_EDGES 196608
#define N_GRAPHS 256
#define DEG 6
#define HID 128
#define RVD 16
#define EMB 112
#define VOCAB 128
#define TGT 256
#define DEPTH 5

#define LOG7 1.9459101090932196f
#define ILOG7 0.5138983423697507f

typedef __hip_bfloat16 bf16;
using frag_ab = __attribute__((ext_vector_type(8))) short;   // 8 bf16
using frag_cd = __attribute__((ext_vector_type(4))) float;   // 4 f32
typedef float f32x2 __attribute__((ext_vector_type(2)));

static __device__ __forceinline__ float b2f(bf16 x) { return __bfloat162float(x); }
static __device__ __forceinline__ bf16  f2b(float x) { return __float2bfloat16(x); }
static __device__ __forceinline__ float us2f(unsigned short u) {
    unsigned int x = ((unsigned int)u) << 16;
    return __uint_as_float(x);
}
static __device__ __forceinline__ unsigned short f2us(float x) {
    bf16 b = __float2bfloat16(x);
    return *reinterpret_cast<unsigned short*>(&b);
}

// ---------------- unified prep: encode + packs + bond table, one dispatch ----------------
#define PB_ENC  16384
#define PB_WB   (PB_ENC + 640)
#define PB_WC   (PB_WB + 1600)
#define PB_WR   (PB_WC + 80)
#define PB_CODE (PB_WR + 768)
#define PB_T    (PB_CODE + 320)

__global__ __launch_bounds__(256) void prep_k(const int* __restrict__ af, const float* __restrict__ rx,
                                              const float* __restrict__ aemb, bf16* __restrict__ h,
                                              const float* __restrict__ preW, const float* __restrict__ preB,
                                              const float* __restrict__ postW,
                                              const int* __restrict__ bfeat, const float* __restrict__ bemb,
                                              bf16* __restrict__ wb, bf16* __restrict__ wc,
                                              bf16* __restrict__ wrB, unsigned char* __restrict__ codeA,
                                              bf16* __restrict__ Tb) {
    int blk = blockIdx.x, tid = threadIdx.x;
    if (blk < PB_ENC) {
        int v = blk * 2 + (tid >> 7), c = tid & 127;
        float val;
        if (c < EMB) {
            val = 0.f;
            #pragma unroll
            for (int i = 0; i < 9; ++i) {
                int f = af[v * 9 + i];
                val += aemb[(i * VOCAB + f) * EMB + c];
            }
        } else {
            val = rx[v * RVD + (c - EMB)];
        }
        h[(size_t)v * HID + c] = f2b(val);
    } else if (blk < PB_WB) {
        int idx = (blk - PB_ENC) * 256 + tid;
        if (idx < DEPTH * 32768) {
            int j = idx & 7, L = (idx >> 3) & 63, nt = (idx >> 9) & 15, ks = (idx >> 13) & 3, l = idx >> 15;
            int k = ks * 32 + ((L >> 4) * 8) + j;
            int n = nt * 16 + (L & 15);
            const float* W = preW + (size_t)l * 384 * 128;
            float v = (n < 128) ? W[k * 128 + n] : W[(128 + k) * 128 + (n - 128)];
            wb[idx] = f2b(v);
        }
    } else if (blk < PB_WC) {
        int idx = (blk - PB_WB) * 256 + tid;
        if (idx < DEPTH * 81920) {
            int j = idx & 7, L = (idx >> 3) & 63, nt = (idx >> 9) & 7;
            int t = idx >> 12;
            int ks = t % 20, l = t / 20;
            int k = ks * 32 + ((L >> 4) * 8) + j;
            int n = nt * 16 + (L & 15);
            const float* W = postW + (size_t)l * 1664 * 128;
            float v;
            if (k < 128) {
                v = W[k * 128 + n];
            } else {
                int jj = k - 128;
                v = W[(128 + jj) * 128 + n] + LOG7 * W[(640 + jj) * 128 + n] + ILOG7 * W[(1152 + jj) * 128 + n];
            }
            wc[idx] = f2b(v);
        }
    } else if (blk < PB_WR) {
        int idx = (blk - PB_WC) * 256 + tid;
        if (idx < DEPTH * 4096) {
            int j = idx & 7, L = (idx >> 3) & 63, nt = (idx >> 9) & 7, l = idx >> 12;
            int k = ((L >> 4) * 8) + j;
            int n = nt * 16 + (L & 15);
            float v = (k < 16) ? preW[(size_t)l * 384 * 128 + (368 + k) * 128 + n] : 0.f;
            wrB[idx] = f2b(v);
        }
    } else if (blk < PB_CODE) {
        int e = (blk - PB_WR) * 256 + tid;
        if (e < N_EDGES)
            codeA[e] = (unsigned char)(bfeat[e * 3] | (bfeat[e * 3 + 1] << 2) | (bfeat[e * 3 + 2] << 4));
    } else {
        if (tid < 128) {
            int t = blk - PB_CODE;
            int l = t >> 6, cd = t & 63, c = tid;
            int f0 = cd & 3, f1 = (cd >> 2) & 3, f2 = cd >> 4;
            const float* W = preW + (size_t)l * 384 * 128 + 256 * 128;
            float acc = preB[l * 128 + c];
            #pragma unroll 4
            for (int k = 0; k < EMB; ++k) {
                float bsk = bemb[(0 * VOCAB + f0) * EMB + k]
                          + bemb[(1 * VOCAB + f1) * EMB + k]
                          + bemb[(2 * VOCAB + f2) * EMB + k];
                acc += bsk * W[k * 128 + c];
            }
            Tb[(size_t)(l * 64 + cd) * 128 + c] = f2b(acc);
        }
    }
}

// ---------------- layer-0 Z12 GEMM: z12 = h @ wb0 ----------------
__global__ __launch_bounds__(256) void gemm_z12(const bf16* __restrict__ A,
                                                const bf16* __restrict__ Bp,
                                                bf16* __restrict__ C) {
    int lane = threadIdx.x & 63;
    int wave = threadIdx.x >> 6;
    int m = lane & 15, quad = lane >> 4;
    int row0 = blockIdx.x * 64 + wave * 16;

    frag_cd acc[16];
    #pragma unroll
    for (int nt = 0; nt < 16; ++nt)
        #pragma unroll
        for (int i = 0; i < 4; ++i) acc[nt][i] = 0.f;

    const frag_ab* Bf = (const frag_ab*)Bp;
    const bf16* arow = A + (size_t)(row0 + m) * 128;
    #pragma unroll
    for (int ks = 0; ks < 4; ++ks) {
        frag_ab a = *(const frag_ab*)(arow + ks * 32 + quad * 8);
        #pragma unroll
        for (int nt = 0; nt < 16; ++nt) {
            frag_ab b = Bf[(ks * 16 + nt) * 64 + lane];
            acc[nt] = __builtin_amdgcn_mfma_f32_16x16x32_bf16(a, b, acc[nt], 0, 0, 0);
        }
    }
    #pragma unroll
    for (int nt = 0; nt < 16; ++nt) {
        int col = nt * 16 + m;
        #pragma unroll
        for (int r = 0; r < 4; ++r) {
            int row = row0 + quad * 4 + r;
            C[(size_t)row * 256 + col] = f2b(acc[nt][r]);
        }
    }
}

// ---------------- fully fused layer v2: barrier-free agg + posttrans + residual + next-z12 ----------------
// Block = 64 nodes, 512 threads / 8 waves, 2 blocks/CU (78.8 KB LDS).
// agg phase: wave w independently aggregates nodes row0+w*8..+7 (lane = 2 channels),
// software-pipelined gathers (idx depth 2, z1/tv/z2 depth 1). rdot computed in-lane:
// 16 packed-f32 FMAs per channel pair, rand_edge staged per-wave in a small LDS
// broadcast buffer (re-filled once at node 4). NO barriers until the GEMM phase.
// GEMM phase: posttrans (h + agg_lds) + residual + next-layer z12, as before.
__global__ __launch_bounds__(512, 4) void fused_layer(bf16* __restrict__ h,
                                                      const bf16* __restrict__ Zcur,
                                                      const int* __restrict__ src,
                                                      const unsigned char* __restrict__ code,
                                                      const float* __restrict__ rand_edge,
                                                      const bf16* __restrict__ Tb,
                                                      const float* __restrict__ Wr,
                                                      const bf16* __restrict__ Bp,
                                                      const float* __restrict__ bias,
                                                      const bf16* __restrict__ Bn,
                                                      bf16* __restrict__ Znext) {
    __shared__ __align__(16) bf16 agg_lds[64 * 520];   // 66,560 B
    __shared__ __align__(16) float relds[8][384];      // 12,288 B; per-wave rand_edge broadcast

    int tid = threadIdx.x;
    int lane = tid & 63, wave = tid >> 6;
    int m = lane & 15, quad = lane >> 4;
    int row0 = blockIdx.x * 64;

    const unsigned short* Zu = (const unsigned short*)Zcur;
    const unsigned short* Tu = (const unsigned short*)Tb;
    unsigned short* Ag = (unsigned short*)agg_lds;
    int c = lane * 2;

    // ================= agg phase: per-wave, no barriers =================
    {
        const int vbase = row0 + wave * 8;

        // Wr columns (c, c+1) in registers: 16 x f32x2
        f32x2 wr2[16];
        #pragma unroll
        for (int k = 0; k < 16; ++k) {
            float2 w2 = *(const float2*)(Wr + k * 128 + c);
            wr2[k].x = w2.x; wr2[k].y = w2.y;
        }

        // stage rand_edge half 0 (nodes 0..3 = 384 floats) into relds[wave]
        {
            const float2* rb = (const float2*)(rand_edge + (size_t)vbase * 96);
            float2 a0 = rb[lane], a1 = rb[lane + 64], a2 = rb[lane + 128];
            float2* rl = (float2*)relds[wave];
            rl[lane] = a0; rl[lane + 64] = a1; rl[lane + 128] = a2;
        }
        float2 rh0, rh1, rh2;   // half-1 staging regs (loaded at i==2, ds_written at i==4)

        int svs[2][6]; int cds[2][6];
        ushort2 z1u[2][6], tvu[2][6], z2u[2];

        // idx(0) -> slot 0
        {
            const int2* sp = (const int2*)(src + vbase * 6);
            int2 a = sp[0], b = sp[1], d = sp[2];
            svs[0][0] = a.x; svs[0][1] = a.y; svs[0][2] = b.x;
            svs[0][3] = b.y; svs[0][4] = d.x; svs[0][5] = d.y;
            const unsigned short* cp = (const unsigned short*)(code + vbase * 6);
            unsigned short x = cp[0], y = cp[1], z = cp[2];
            cds[0][0] = x & 255; cds[0][1] = x >> 8; cds[0][2] = y & 255;
            cds[0][3] = y >> 8;  cds[0][4] = z & 255; cds[0][5] = z >> 8;
        }
        // gathers(0) -> slot 0
        z2u[0] = *(const ushort2*)(Zu + (size_t)vbase * 256 + 128 + c);
        #pragma unroll
        for (int j = 0; j < 6; ++j) z1u[0][j] = *(const ushort2*)(Zu + (size_t)svs[0][j] * 256 + c);
        #pragma unroll
        for (int j = 0; j < 6; ++j) tvu[0][j] = *(const ushort2*)(Tu + cds[0][j] * 128 + c);
        // idx(1) -> slot 1
        {
            const int2* sp = (const int2*)(src + (vbase + 1) * 6);
            int2 a = sp[0], b = sp[1], d = sp[2];
            svs[1][0] = a.x; svs[1][1] = a.y; svs[1][2] = b.x;
            svs[1][3] = b.y; svs[1][4] = d.x; svs[1][5] = d.y;
            const unsigned short* cp = (const unsigned short*)(code + (vbase + 1) * 6);
            unsigned short x = cp[0], y = cp[1], z = cp[2];
            cds[1][0] = x & 255; cds[1][1] = x >> 8; cds[1][2] = y & 255;
            cds[1][3] = y >> 8;  cds[1][4] = z & 255; cds[1][5] = z >> 8;
        }

        #pragma unroll
        for (int i = 0; i < 8; ++i) {
            const int s = i & 1, t = s ^ 1;
            if (i == 2) {   // issue half-1 rand_edge loads (in flight through i=2,3)
                const float2* rb2 = (const float2*)(rand_edge + (size_t)(vbase + 4) * 96);
                rh0 = rb2[lane]; rh1 = rb2[lane + 64]; rh2 = rb2[lane + 128];
            }
            if (i == 4) {   // after compute(3) read half 0 (in-order LDS per wave)
                float2* rl = (float2*)relds[wave];
                rl[lane] = rh0; rl[lane + 64] = rh1; rl[lane + 128] = rh2;
            }
            if (i < 7) {    // gathers(i+1) from idx slot t
                z2u[t] = *(const ushort2*)(Zu + (size_t)(vbase + i + 1) * 256 + 128 + c);
                #pragma unroll
                for (int j = 0; j < 6; ++j) z1u[t][j] = *(const ushort2*)(Zu + (size_t)svs[t][j] * 256 + c);
                #pragma unroll
                for (int j = 0; j < 6; ++j) tvu[t][j] = *(const ushort2*)(Tu + cds[t][j] * 128 + c);
            }
            if (i < 6) {    // idx(i+2) -> slot s (node i's gathers already issued)
                const int2* sp = (const int2*)(src + (vbase + i + 2) * 6);
                int2 a = sp[0], b = sp[1], d = sp[2];
                svs[s][0] = a.x; svs[s][1] = a.y; svs[s][2] = b.x;
                svs[s][3] = b.y; svs[s][4] = d.x; svs[s][5] = d.y;
                const unsigned short* cp = (const unsigned short*)(code + (vbase + i + 2) * 6);
                unsigned short x = cp[0], y = cp[1], z = cp[2];
                cds[s][0] = x & 255; cds[s][1] = x >> 8; cds[s][2] = y & 255;
                cds[s][3] = y >> 8;  cds[s][4] = z & 255; cds[s][5] = z >> 8;
            }

            // ---- compute node i (gather slot s) ----
            float z2a = us2f(z2u[s].x), z2b = us2f(z2u[s].y);
            f32x2 s2  = {0.f, 0.f}, ss2 = {0.f, 0.f};
            f32x2 mx2 = {-1e30f, -1e30f}, mn2 = {1e30f, 1e30f};
            #pragma unroll
            for (int j = 0; j < 6; ++j) {
                const float4* rp = (const float4*)&relds[wave][(i & 3) * 96 + j * 16];
                float4 r0 = rp[0], r1 = rp[1], r2 = rp[2], r3 = rp[3];  // LDS broadcast
                f32x2 v2;
                v2.x = us2f(z1u[s][j].x) + z2a + us2f(tvu[s][j].x);
                v2.y = us2f(z1u[s][j].y) + z2b + us2f(tvu[s][j].y);
                float rk[16] = {r0.x, r0.y, r0.z, r0.w, r1.x, r1.y, r1.z, r1.w,
                                r2.x, r2.y, r2.z, r2.w, r3.x, r3.y, r3.z, r3.w};
                #pragma unroll
                for (int k = 0; k < 16; ++k) v2 += rk[k] * wr2[k];
                v2 = __builtin_elementwise_max(v2, (f32x2){0.f, 0.f});
                s2 += v2;
                ss2 += v2 * v2;
                mx2 = __builtin_elementwise_max(mx2, v2);
                mn2 = __builtin_elementwise_min(mn2, v2);
            }
            f32x2 mean2 = s2 * (1.f / 6.f);
            f32x2 msq2  = ss2 * (1.f / 6.f);
            f32x2 var2  = __builtin_elementwise_max(msq2 - mean2 * mean2, (f32x2){0.f, 0.f});
            float sda = sqrtf(var2.x + 1e-5f), sdb = sqrtf(var2.y + 1e-5f);
            int lrow = wave * 8 + i;
            size_t base = (size_t)lrow * 520 + c;
            *(ushort2*)(Ag + base)       = make_ushort2(f2us(mean2.x), f2us(mean2.y));
            *(ushort2*)(Ag + base + 128) = make_ushort2(f2us(mx2.x),   f2us(mx2.y));
            *(ushort2*)(Ag + base + 256) = make_ushort2(f2us(mn2.x),   f2us(mn2.y));
            *(ushort2*)(Ag + base + 384) = make_ushort2(f2us(sda),     f2us(sdb));
        }
    }
    __syncthreads();   // agg tile complete -> GEMM phase may read any row

    // ================= GEMM phase: posttrans + residual + next-layer Z12 =================
    int rt = wave & 3, nh = wave >> 2;
    int rowA = row0 + rt * 16 + m;

    frag_cd acc[4];
    #pragma unroll
    for (int nt = 0; nt < 4; ++nt)
        #pragma unroll
        for (int i = 0; i < 4; ++i) acc[nt][i] = 0.f;

    const frag_ab* Bf = (const frag_ab*)Bp;
    const bf16* arow = h + (size_t)rowA * 128;
    #pragma unroll
    for (int ks = 0; ks < 4; ++ks) {
        frag_ab a = *(const frag_ab*)(arow + ks * 32 + quad * 8);
        #pragma unroll
        for (int nt = 0; nt < 4; ++nt) {
            frag_ab b = Bf[(ks * 8 + nh * 4 + nt) * 64 + lane];
            acc[nt] = __builtin_amdgcn_mfma_f32_16x16x32_bf16(a, b, acc[nt], 0, 0, 0);
        }
    }
    const bf16* grow = agg_lds + (size_t)(rt * 16 + m) * 520;
    #pragma unroll
    for (int ks = 0; ks < 16; ++ks) {
        frag_ab a = *(const frag_ab*)(grow + ks * 32 + quad * 8);
        #pragma unroll
        for (int nt = 0; nt < 4; ++nt) {
            frag_ab b = Bf[((4 + ks) * 8 + nh * 4 + nt) * 64 + lane];
            acc[nt] = __builtin_amdgcn_mfma_f32_16x16x32_bf16(a, b, acc[nt], 0, 0, 0);
        }
    }

    __syncthreads();   // all waves done reading h rows + agg_lds before writes

    bf16* newh = agg_lds;   // alias: agg tile is dead; stride 136 (b128-aligned rows)
    #pragma unroll
    for (int nt = 0; nt < 4; ++nt) {
        int col = nh * 64 + nt * 16 + m;
        float bs_ = bias[col];
        #pragma unroll
        for (int r2 = 0; r2 < 4; ++r2) {
            int lr = rt * 16 + quad * 4 + r2;
            int row = row0 + lr;
            float nv = acc[nt][r2] + bs_ + b2f(h[(size_t)row * HID + col]);
            bf16 bv2 = f2b(nv);
            h[(size_t)row * HID + col] = bv2;
            newh[lr * 136 + col] = bv2;
        }
    }

    if (Bn) {
        __syncthreads();
        const frag_ab* Bf2 = (const frag_ab*)Bn;
        frag_cd a2[8];
        #pragma unroll
        for (int nt = 0; nt < 8; ++nt)
            #pragma unroll
            for (int i = 0; i < 4; ++i) a2[nt][i] = 0.f;
        #pragma unroll
        for (int ks = 0; ks < 4; ++ks) {
            frag_ab a = *(const frag_ab*)&newh[(rt * 16 + m) * 136 + ks * 32 + quad * 8];
            #pragma unroll
            for (int nt = 0; nt < 8; ++nt) {
                frag_ab b = Bf2[(ks * 16 + nh * 8 + nt) * 64 + lane];
                a2[nt] = __builtin_amdgcn_mfma_f32_16x16x32_bf16(a, b, a2[nt], 0, 0, 0);
            }
        }
        #pragma unroll
        for (int nt = 0; nt < 8; ++nt) {
            int col = nh * 128 + nt * 16 + m;
            #pragma unroll
            for (int r2 = 0; r2 < 4; ++r2) {
                int row = row0 + rt * 16 + quad * 4 + r2;
                Znext[(size_t)row * 256 + col] = f2b(a2[nt][r2]);
            }
        }
    }
}

// ---------------- readout ----------------
__global__ __launch_bounds__(128) void readout(const bf16* __restrict__ h, const float* __restrict__ W1,
                                               const float* __restrict__ b1, const float* __restrict__ W2,
                                               const float* __restrict__ b2, float* __restrict__ out) {
    __shared__ float r[384];
    __shared__ float y1[128];
    int g = blockIdx.x, c = threadIdx.x;
    float s = 0.f, mx = -1e30f;
    for (int v = 0; v < 128; ++v) {
        float hv = b2f(h[((size_t)g * 128 + v) * HID + c]);
        s += hv; mx = fmaxf(mx, hv);
    }
    r[c] = s * (1.f / 128.f);
    r[128 + c] = s;
    r[256 + c] = mx;
    __syncthreads();
    float a1 = b1[c];
    for (int k = 0; k < 384; ++k) a1 += r[k] * W1[k * 128 + c];
    y1[c] = fmaxf(a1, 0.f);
    __syncthreads();
    #pragma unroll
    for (int o = 0; o < 2; ++o) {
        int t = c + o * 128;
        float a2 = b2[t];
        for (int k = 0; k < 128; ++k) a2 += y1[k] * W2[k * 256 + t];
        out[(size_t)g * 256 + t] = a2;
    }
}

// ---------------- launch ----------------
extern "C" void kernel_launch(void* const* d_in, const int* in_sizes, int n_in,
                              void* d_out, int out_size, void* d_ws, size_t ws_size,
                              hipStream_t stream) {
    const int*   atom_feats = (const int*)d_in[0];
    const int*   bond_feats = (const int*)d_in[1];
    const int*   src        = (const int*)d_in[2];
    const float* rand_x     = (const float*)d_in[6];
    const float* rand_edge  = (const float*)d_in[7];
    const float* atom_emb   = (const float*)d_in[8];
    const float* bond_emb   = (const float*)d_in[9];
    const float* pre_W      = (const float*)d_in[10];
    const float* pre_b      = (const float*)d_in[11];
    const float* post_W     = (const float*)d_in[12];
    const float* post_b     = (const float*)d_in[13];
    const float* ro_W1      = (const float*)d_in[14];
    const float* ro_b1      = (const float*)d_in[15];
    const float* ro_W2      = (const float*)d_in[16];
    const float* ro_b2      = (const float*)d_in[17];

    char* p = (char*)d_ws;
    auto alloc = [&](size_t bytes) {
        char* r = p;
        p += (bytes + 255) & ~(size_t)255;
        return r;
    };
    bf16*  h    = (bf16*) alloc((size_t)N_NODES * HID * 2);      // 8 MB (bf16 state)
    bf16*  z12a = (bf16*) alloc((size_t)N_NODES * 256 * 2);      // 16 MB (ping)
    bf16*  z12b = (bf16*) alloc((size_t)N_NODES * 256 * 2);      // 16 MB (pong)
    bf16*  wb   = (bf16*) alloc((size_t)DEPTH * 32768 * 2);
    bf16*  wc   = (bf16*) alloc((size_t)DEPTH * 81920 * 2);
    bf16*  wrB  = (bf16*) alloc((size_t)DEPTH * 4096 * 2);       // 40 KB (legacy pack, unused)
    bf16*  Tb   = (bf16*) alloc((size_t)DEPTH * 64 * 128 * 2);   // 80 KB
    unsigned char* code = (unsigned char*)alloc(N_EDGES);        // 192 KB

    // unified prep (encode + all packs + bond table)
    prep_k<<<PB_T, 256, 0, stream>>>(atom_feats, rand_x, atom_emb, h,
                                     pre_W, pre_b, post_W,
                                     bond_feats, bond_emb,
                                     wb, wc, wrB, code, Tb);

    // layer-0 Z12
    gemm_z12<<<N_NODES / 64, 256, 0, stream>>>(h, wb, z12a);

    bf16* zc = z12a;
    bf16* zn = z12b;
    for (int l = 0; l < DEPTH; ++l) {
        const bf16* wbn = (l + 1 < DEPTH) ? (wb + (size_t)(l + 1) * 32768) : nullptr;
        fused_layer<<<N_NODES / 64, 512, 0, stream>>>(
            h, zc, src, code, rand_edge,
            Tb + (size_t)l * 8192,
            pre_W + (size_t)l * 384 * 128 + 368 * 128,   // Wr: rand-edge rows of pretrans W
            wc + (size_t)l * 81920,
            post_b + l * HID,
            wbn, zn);
        bf16* t = zc; zc = zn; zn = t;
    }

    readout<<<N_GRAPHS, 128, 0, stream>>>(h, ro_W1, ro_b1, ro_W2, ro_b2, (float*)d_out);
}

// Round 4
// 333.227 us; speedup vs baseline: 1.1384x; 1.0134x over previous
//
#include <hip/hip_runtime.h>
#include <hip/hip_bf16.h>

#define N_NODES 32768
#define N_EDGES 196608
#define N_GRAPHS 256
#define DEG 6
#define HID 128
#define RVD 16
#define EMB 112
#define VOCAB 128
#define TGT 256
#define DEPTH 5

#define LOG7 1.9459101090932196f
#define ILOG7 0.5138983423697507f

typedef __hip_bfloat16 bf16;
using frag_ab = __attribute__((ext_vector_type(8))) short;   // 8 bf16
using frag_cd = __attribute__((ext_vector_type(4))) float;   // 4 f32
typedef float f32x2 __attribute__((ext_vector_type(2)));

static __device__ __forceinline__ float b2f(bf16 x) { return __bfloat162float(x); }
static __device__ __forceinline__ bf16  f2b(float x) { return __float2bfloat16(x); }
static __device__ __forceinline__ float us2f(unsigned short u) {
    unsigned int x = ((unsigned int)u) << 16;
    return __uint_as_float(x);
}
static __device__ __forceinline__ unsigned short f2us(float x) {
    bf16 b = __float2bfloat16(x);
    return *reinterpret_cast<unsigned short*>(&b);
}

// ---------------- unified prep: encode + packs + bond table, one dispatch ----------------
#define PB_ENC  16384
#define PB_WB   (PB_ENC + 640)
#define PB_WC   (PB_WB + 1600)
#define PB_WR   (PB_WC + 80)
#define PB_CODE (PB_WR + 768)
#define PB_T    (PB_CODE + 320)

__global__ __launch_bounds__(256) void prep_k(const int* __restrict__ af, const float* __restrict__ rx,
                                              const float* __restrict__ aemb, bf16* __restrict__ h,
                                              const float* __restrict__ preW, const float* __restrict__ preB,
                                              const float* __restrict__ postW,
                                              const int* __restrict__ bfeat, const float* __restrict__ bemb,
                                              bf16* __restrict__ wb, bf16* __restrict__ wc,
                                              bf16* __restrict__ wrB, unsigned char* __restrict__ codeA,
                                              bf16* __restrict__ Tb) {
    int blk = blockIdx.x, tid = threadIdx.x;
    if (blk < PB_ENC) {
        int v = blk * 2 + (tid >> 7), c = tid & 127;
        float val;
        if (c < EMB) {
            val = 0.f;
            #pragma unroll
            for (int i = 0; i < 9; ++i) {
                int f = af[v * 9 + i];
                val += aemb[(i * VOCAB + f) * EMB + c];
            }
        } else {
            val = rx[v * RVD + (c - EMB)];
        }
        h[(size_t)v * HID + c] = f2b(val);
    } else if (blk < PB_WB) {
        int idx = (blk - PB_ENC) * 256 + tid;
        if (idx < DEPTH * 32768) {
            int j = idx & 7, L = (idx >> 3) & 63, nt = (idx >> 9) & 15, ks = (idx >> 13) & 3, l = idx >> 15;
            int k = ks * 32 + ((L >> 4) * 8) + j;
            int n = nt * 16 + (L & 15);
            const float* W = preW + (size_t)l * 384 * 128;
            float v = (n < 128) ? W[k * 128 + n] : W[(128 + k) * 128 + (n - 128)];
            wb[idx] = f2b(v);
        }
    } else if (blk < PB_WC) {
        int idx = (blk - PB_WB) * 256 + tid;
        if (idx < DEPTH * 81920) {
            int j = idx & 7, L = (idx >> 3) & 63, nt = (idx >> 9) & 7;
            int t = idx >> 12;
            int ks = t % 20, l = t / 20;
            int k = ks * 32 + ((L >> 4) * 8) + j;
            int n = nt * 16 + (L & 15);
            const float* W = postW + (size_t)l * 1664 * 128;
            float v;
            if (k < 128) {
                v = W[k * 128 + n];
            } else {
                int jj = k - 128;
                v = W[(128 + jj) * 128 + n] + LOG7 * W[(640 + jj) * 128 + n] + ILOG7 * W[(1152 + jj) * 128 + n];
            }
            wc[idx] = f2b(v);
        }
    } else if (blk < PB_WR) {
        int idx = (blk - PB_WC) * 256 + tid;
        if (idx < DEPTH * 4096) {
            int j = idx & 7, L = (idx >> 3) & 63, nt = (idx >> 9) & 7, l = idx >> 12;
            int k = ((L >> 4) * 8) + j;
            int n = nt * 16 + (L & 15);
            float v = (k < 16) ? preW[(size_t)l * 384 * 128 + (368 + k) * 128 + n] : 0.f;
            wrB[idx] = f2b(v);
        }
    } else if (blk < PB_CODE) {
        int e = (blk - PB_WR) * 256 + tid;
        if (e < N_EDGES)
            codeA[e] = (unsigned char)(bfeat[e * 3] | (bfeat[e * 3 + 1] << 2) | (bfeat[e * 3 + 2] << 4));
    } else {
        if (tid < 128) {
            int t = blk - PB_CODE;
            int l = t >> 6, cd = t & 63, c = tid;
            int f0 = cd & 3, f1 = (cd >> 2) & 3, f2 = cd >> 4;
            const float* W = preW + (size_t)l * 384 * 128 + 256 * 128;
            float acc = preB[l * 128 + c];
            #pragma unroll 4
            for (int k = 0; k < EMB; ++k) {
                float bsk = bemb[(0 * VOCAB + f0) * EMB + k]
                          + bemb[(1 * VOCAB + f1) * EMB + k]
                          + bemb[(2 * VOCAB + f2) * EMB + k];
                acc += bsk * W[k * 128 + c];
            }
            Tb[(size_t)(l * 64 + cd) * 128 + c] = f2b(acc);
        }
    }
}

// ---------------- layer-0 Z12 GEMM: z12 = h @ wb0 ----------------
__global__ __launch_bounds__(256) void gemm_z12(const bf16* __restrict__ A,
                                                const bf16* __restrict__ Bp,
                                                bf16* __restrict__ C) {
    int lane = threadIdx.x & 63;
    int wave = threadIdx.x >> 6;
    int m = lane & 15, quad = lane >> 4;
    int row0 = blockIdx.x * 64 + wave * 16;

    frag_cd acc[16];
    #pragma unroll
    for (int nt = 0; nt < 16; ++nt)
        #pragma unroll
        for (int i = 0; i < 4; ++i) acc[nt][i] = 0.f;

    const frag_ab* Bf = (const frag_ab*)Bp;
    const bf16* arow = A + (size_t)(row0 + m) * 128;
    #pragma unroll
    for (int ks = 0; ks < 4; ++ks) {
        frag_ab a = *(const frag_ab*)(arow + ks * 32 + quad * 8);
        #pragma unroll
        for (int nt = 0; nt < 16; ++nt) {
            frag_ab b = Bf[(ks * 16 + nt) * 64 + lane];
            acc[nt] = __builtin_amdgcn_mfma_f32_16x16x32_bf16(a, b, acc[nt], 0, 0, 0);
        }
    }
    #pragma unroll
    for (int nt = 0; nt < 16; ++nt) {
        int col = nt * 16 + m;
        #pragma unroll
        for (int r = 0; r < 4; ++r) {
            int row = row0 + quad * 4 + r;
            C[(size_t)row * 256 + col] = f2b(acc[nt][r]);
        }
    }
}

// ---------------- fully fused layer v3 ----------------
// Block = 64 nodes, 512 threads / 8 waves, 2 blocks/CU (78.8 KB LDS).
// agg phase: wave w aggregates nodes row0+w*8..+7, gathers software-pipelined DEPTH-2
// (idx 4 ahead, gathers 2 ahead, mod-3 slots). rdot in-lane (16 pk-FMA per channel pair),
// rand_edge via per-wave LDS broadcast. No barriers in agg.
// GEMM phase re-tiled for B-reuse (TCP-line-bound fix): wave = (mh 0..1, ng 0..3);
// each wave computes 32 rows x 32 cols; every B-fragment reused across 2 m-tiles
// => B-frag TCP traffic halved vs (rt,nh) tiling (was 4x weight redundancy, now 2x).
__global__ __launch_bounds__(512, 4) void fused_layer(bf16* __restrict__ h,
                                                      const bf16* __restrict__ Zcur,
                                                      const int* __restrict__ src,
                                                      const unsigned char* __restrict__ code,
                                                      const float* __restrict__ rand_edge,
                                                      const bf16* __restrict__ Tb,
                                                      const float* __restrict__ Wr,
                                                      const bf16* __restrict__ Bp,
                                                      const float* __restrict__ bias,
                                                      const bf16* __restrict__ Bn,
                                                      bf16* __restrict__ Znext) {
    __shared__ __align__(16) bf16 agg_lds[64 * 520];   // 66,560 B
    __shared__ __align__(16) float relds[8][384];      // 12,288 B; per-wave rand_edge broadcast

    int tid = threadIdx.x;
    int lane = tid & 63, wave = tid >> 6;
    int ml = lane & 15, quad = lane >> 4;
    int row0 = blockIdx.x * 64;

    const unsigned short* Zu = (const unsigned short*)Zcur;
    const unsigned short* Tu = (const unsigned short*)Tb;
    unsigned short* Ag = (unsigned short*)agg_lds;
    int c = lane * 2;

    // ================= agg phase: per-wave, no barriers, depth-2 pipeline =================
    {
        const int vbase = row0 + wave * 8;

        // Wr columns (c, c+1) in registers: 16 x f32x2
        f32x2 wr2[16];
        #pragma unroll
        for (int k = 0; k < 16; ++k) {
            float2 w2 = *(const float2*)(Wr + k * 128 + c);
            wr2[k].x = w2.x; wr2[k].y = w2.y;
        }

        // stage rand_edge half 0 (nodes 0..3 = 384 floats) into relds[wave]
        {
            const float2* rb = (const float2*)(rand_edge + (size_t)vbase * 96);
            float2 a0 = rb[lane], a1 = rb[lane + 64], a2 = rb[lane + 128];
            float2* rl = (float2*)relds[wave];
            rl[lane] = a0; rl[lane + 64] = a1; rl[lane + 128] = a2;
        }
        float2 rh0, rh1, rh2;   // half-1 staging regs (loaded at i==2, ds_written at i==4)

        int svs[2][6]; int cds[2][6];
        ushort2 z1u[3][6], tvu[3][6], z2u[3];

#define LOADIDX(node, slot)                                                        \
        {                                                                          \
            const int2* sp = (const int2*)(src + (size_t)(vbase + (node)) * 6);    \
            int2 a_ = sp[0], b_ = sp[1], d_ = sp[2];                               \
            svs[slot][0] = a_.x; svs[slot][1] = a_.y; svs[slot][2] = b_.x;         \
            svs[slot][3] = b_.y; svs[slot][4] = d_.x; svs[slot][5] = d_.y;         \
            const unsigned short* cp = (const unsigned short*)(code + (vbase + (node)) * 6); \
            unsigned short x_ = cp[0], y_ = cp[1], z_ = cp[2];                     \
            cds[slot][0] = x_ & 255; cds[slot][1] = x_ >> 8; cds[slot][2] = y_ & 255; \
            cds[slot][3] = y_ >> 8;  cds[slot][4] = z_ & 255; cds[slot][5] = z_ >> 8; \
        }

#define GATHER(node, gs, is)                                                       \
        {                                                                          \
            z2u[gs] = *(const ushort2*)(Zu + (size_t)(vbase + (node)) * 256 + 128 + c); \
            _Pragma("unroll")                                                      \
            for (int j = 0; j < 6; ++j)                                            \
                z1u[gs][j] = *(const ushort2*)(Zu + (size_t)svs[is][j] * 256 + c); \
            _Pragma("unroll")                                                      \
            for (int j = 0; j < 6; ++j)                                            \
                tvu[gs][j] = *(const ushort2*)(Tu + cds[is][j] * 128 + c);         \
        }

        LOADIDX(0, 0); LOADIDX(1, 1);
        GATHER(0, 0, 0);
        LOADIDX(2, 0);
        GATHER(1, 1, 1);
        LOADIDX(3, 1);

        #pragma unroll
        for (int i = 0; i < 8; ++i) {
            const int s = i % 3;
            if (i == 2) {   // issue half-1 rand_edge loads (in flight through i=2,3)
                const float2* rb2 = (const float2*)(rand_edge + (size_t)(vbase + 4) * 96);
                rh0 = rb2[lane]; rh1 = rb2[lane + 64]; rh2 = rb2[lane + 128];
            }
            if (i == 4) {   // after compute(3) read half 0 (in-order LDS per wave)
                float2* rl = (float2*)relds[wave];
                rl[lane] = rh0; rl[lane + 64] = rh1; rl[lane + 128] = rh2;
            }
            if (i < 6) GATHER(i + 2, (i + 2) % 3, i & 1);   // gathers 2 nodes ahead
            if (i < 4) LOADIDX(i + 4, i & 1);               // idx 4 nodes ahead

            // ---- compute node i (gather slot s) ----
            float z2a = us2f(z2u[s].x), z2b = us2f(z2u[s].y);
            f32x2 s2  = {0.f, 0.f}, ss2 = {0.f, 0.f};
            f32x2 mx2 = {-1e30f, -1e30f}, mn2 = {1e30f, 1e30f};
            #pragma unroll
            for (int j = 0; j < 6; ++j) {
                const float4* rp = (const float4*)&relds[wave][(i & 3) * 96 + j * 16];
                float4 r0 = rp[0], r1 = rp[1], r2 = rp[2], r3 = rp[3];  // LDS broadcast
                f32x2 v2;
                v2.x = us2f(z1u[s][j].x) + z2a + us2f(tvu[s][j].x);
                v2.y = us2f(z1u[s][j].y) + z2b + us2f(tvu[s][j].y);
                float rk[16] = {r0.x, r0.y, r0.z, r0.w, r1.x, r1.y, r1.z, r1.w,
                                r2.x, r2.y, r2.z, r2.w, r3.x, r3.y, r3.z, r3.w};
                #pragma unroll
                for (int k = 0; k < 16; ++k) v2 += rk[k] * wr2[k];
                v2 = __builtin_elementwise_max(v2, (f32x2){0.f, 0.f});
                s2 += v2;
                ss2 += v2 * v2;
                mx2 = __builtin_elementwise_max(mx2, v2);
                mn2 = __builtin_elementwise_min(mn2, v2);
            }
            f32x2 mean2 = s2 * (1.f / 6.f);
            f32x2 msq2  = ss2 * (1.f / 6.f);
            f32x2 var2  = __builtin_elementwise_max(msq2 - mean2 * mean2, (f32x2){0.f, 0.f});
            float sda = sqrtf(var2.x + 1e-5f), sdb = sqrtf(var2.y + 1e-5f);
            int lrow = wave * 8 + i;
            size_t base = (size_t)lrow * 520 + c;
            *(ushort2*)(Ag + base)       = make_ushort2(f2us(mean2.x), f2us(mean2.y));
            *(ushort2*)(Ag + base + 128) = make_ushort2(f2us(mx2.x),   f2us(mx2.y));
            *(ushort2*)(Ag + base + 256) = make_ushort2(f2us(mn2.x),   f2us(mn2.y));
            *(ushort2*)(Ag + base + 384) = make_ushort2(f2us(sda),     f2us(sdb));
        }
#undef LOADIDX
#undef GATHER
    }
    __syncthreads();   // agg tile complete -> GEMM phase may read any row

    // ================= GEMM phase: posttrans + residual + next-layer Z12 =================
    // wave = (mh = wave>>2, ng = wave&3): rows mh*32..+31, cols ng*32..+31.
    int mh = wave >> 2, ng = wave & 3;

    frag_cd acc[2][2];
    #pragma unroll
    for (int m2 = 0; m2 < 2; ++m2)
        #pragma unroll
        for (int nt = 0; nt < 2; ++nt)
            #pragma unroll
            for (int i = 0; i < 4; ++i) acc[m2][nt][i] = 0.f;

    const frag_ab* Bf = (const frag_ab*)Bp;
    // K-slices 0..3 from h (global), 4..19 from agg_lds
    #pragma unroll
    for (int ks = 0; ks < 4; ++ks) {
        frag_ab b0 = Bf[(ks * 8 + ng * 2 + 0) * 64 + lane];
        frag_ab b1 = Bf[(ks * 8 + ng * 2 + 1) * 64 + lane];
        #pragma unroll
        for (int m2 = 0; m2 < 2; ++m2) {
            int mt = mh * 2 + m2;
            frag_ab a = *(const frag_ab*)(h + (size_t)(row0 + mt * 16 + ml) * 128 + ks * 32 + quad * 8);
            acc[m2][0] = __builtin_amdgcn_mfma_f32_16x16x32_bf16(a, b0, acc[m2][0], 0, 0, 0);
            acc[m2][1] = __builtin_amdgcn_mfma_f32_16x16x32_bf16(a, b1, acc[m2][1], 0, 0, 0);
        }
    }
    #pragma unroll
    for (int ks = 0; ks < 16; ++ks) {
        frag_ab b0 = Bf[((4 + ks) * 8 + ng * 2 + 0) * 64 + lane];
        frag_ab b1 = Bf[((4 + ks) * 8 + ng * 2 + 1) * 64 + lane];
        #pragma unroll
        for (int m2 = 0; m2 < 2; ++m2) {
            int mt = mh * 2 + m2;
            frag_ab a = *(const frag_ab*)(agg_lds + (size_t)(mt * 16 + ml) * 520 + ks * 32 + quad * 8);
            acc[m2][0] = __builtin_amdgcn_mfma_f32_16x16x32_bf16(a, b0, acc[m2][0], 0, 0, 0);
            acc[m2][1] = __builtin_amdgcn_mfma_f32_16x16x32_bf16(a, b1, acc[m2][1], 0, 0, 0);
        }
    }

    __syncthreads();   // all waves done reading h rows + agg_lds before writes

    bf16* newh = agg_lds;   // alias: agg tile is dead; stride 136 (b128-aligned rows)
    #pragma unroll
    for (int nt = 0; nt < 2; ++nt) {
        int col = (ng * 2 + nt) * 16 + ml;
        float bs_ = bias[col];
        #pragma unroll
        for (int m2 = 0; m2 < 2; ++m2) {
            #pragma unroll
            for (int r2 = 0; r2 < 4; ++r2) {
                int lr = (mh * 2 + m2) * 16 + quad * 4 + r2;
                int row = row0 + lr;
                float nv = acc[m2][nt][r2] + bs_ + b2f(h[(size_t)row * HID + col]);
                bf16 bv2 = f2b(nv);
                h[(size_t)row * HID + col] = bv2;
                newh[lr * 136 + col] = bv2;
            }
        }
    }

    if (Bn) {
        __syncthreads();
        const frag_ab* Bf2 = (const frag_ab*)Bn;
        frag_cd a2[2][4];
        #pragma unroll
        for (int m2 = 0; m2 < 2; ++m2)
            #pragma unroll
            for (int nt = 0; nt < 4; ++nt)
                #pragma unroll
                for (int i = 0; i < 4; ++i) a2[m2][nt][i] = 0.f;
        #pragma unroll
        for (int ks = 0; ks < 4; ++ks) {
            frag_ab bb[4];
            #pragma unroll
            for (int nt = 0; nt < 4; ++nt)
                bb[nt] = Bf2[(ks * 16 + ng * 4 + nt) * 64 + lane];
            #pragma unroll
            for (int m2 = 0; m2 < 2; ++m2) {
                int mt = mh * 2 + m2;
                frag_ab a = *(const frag_ab*)&newh[(mt * 16 + ml) * 136 + ks * 32 + quad * 8];
                #pragma unroll
                for (int nt = 0; nt < 4; ++nt)
                    a2[m2][nt] = __builtin_amdgcn_mfma_f32_16x16x32_bf16(a, bb[nt], a2[m2][nt], 0, 0, 0);
            }
        }
        #pragma unroll
        for (int m2 = 0; m2 < 2; ++m2) {
            #pragma unroll
            for (int nt = 0; nt < 4; ++nt) {
                int col = (ng * 4 + nt) * 16 + ml;
                #pragma unroll
                for (int r2 = 0; r2 < 4; ++r2) {
                    int row = row0 + (mh * 2 + m2) * 16 + quad * 4 + r2;
                    Znext[(size_t)row * 256 + col] = f2b(a2[m2][nt][r2]);
                }
            }
        }
    }
}

// ---------------- readout ----------------
__global__ __launch_bounds__(128) void readout(const bf16* __restrict__ h, const float* __restrict__ W1,
                                               const float* __restrict__ b1, const float* __restrict__ W2,
                                               const float* __restrict__ b2, float* __restrict__ out) {
    __shared__ float r[384];
    __shared__ float y1[128];
    int g = blockIdx.x, c = threadIdx.x;
    float s = 0.f, mx = -1e30f;
    for (int v = 0; v < 128; ++v) {
        float hv = b2f(h[((size_t)g * 128 + v) * HID + c]);
        s += hv; mx = fmaxf(mx, hv);
    }
    r[c] = s * (1.f / 128.f);
    r[128 + c] = s;
    r[256 + c] = mx;
    __syncthreads();
    float a1 = b1[c];
    for (int k = 0; k < 384; ++k) a1 += r[k] * W1[k * 128 + c];
    y1[c] = fmaxf(a1, 0.f);
    __syncthreads();
    #pragma unroll
    for (int o = 0; o < 2; ++o) {
        int t = c + o * 128;
        float a2 = b2[t];
        for (int k = 0; k < 128; ++k) a2 += y1[k] * W2[k * 256 + t];
        out[(size_t)g * 256 + t] = a2;
    }
}

// ---------------- launch ----------------
extern "C" void kernel_launch(void* const* d_in, const int* in_sizes, int n_in,
                              void* d_out, int out_size, void* d_ws, size_t ws_size,
                              hipStream_t stream) {
    const int*   atom_feats = (const int*)d_in[0];
    const int*   bond_feats = (const int*)d_in[1];
    const int*   src        = (const int*)d_in[2];
    const float* rand_x     = (const float*)d_in[6];
    const float* rand_edge  = (const float*)d_in[7];
    const float* atom_emb   = (const float*)d_in[8];
    const float* bond_emb   = (const float*)d_in[9];
    const float* pre_W      = (const float*)d_in[10];
    const float* pre_b      = (const float*)d_in[11];
    const float* post_W     = (const float*)d_in[12];
    const float* post_b     = (const float*)d_in[13];
    const float* ro_W1      = (const float*)d_in[14];
    const float* ro_b1      = (const float*)d_in[15];
    const float* ro_W2      = (const float*)d_in[16];
    const float* ro_b2      = (const float*)d_in[17];

    char* p = (char*)d_ws;
    auto alloc = [&](size_t bytes) {
        char* r = p;
        p += (bytes + 255) & ~(size_t)255;
        return r;
    };
    bf16*  h    = (bf16*) alloc((size_t)N_NODES * HID * 2);      // 8 MB (bf16 state)
    bf16*  z12a = (bf16*) alloc((size_t)N_NODES * 256 * 2);      // 16 MB (ping)
    bf16*  z12b = (bf16*) alloc((size_t)N_NODES * 256 * 2);      // 16 MB (pong)
    bf16*  wb   = (bf16*) alloc((size_t)DEPTH * 32768 * 2);
    bf16*  wc   = (bf16*) alloc((size_t)DEPTH * 81920 * 2);
    bf16*  wrB  = (bf16*) alloc((size_t)DEPTH * 4096 * 2);       // 40 KB (legacy pack, unused)
    bf16*  Tb   = (bf16*) alloc((size_t)DEPTH * 64 * 128 * 2);   // 80 KB
    unsigned char* code = (unsigned char*)alloc(N_EDGES);        // 192 KB

    // unified prep (encode + all packs + bond table)
    prep_k<<<PB_T, 256, 0, stream>>>(atom_feats, rand_x, atom_emb, h,
                                     pre_W, pre_b, post_W,
                                     bond_feats, bond_emb,
                                     wb, wc, wrB, code, Tb);

    // layer-0 Z12
    gemm_z12<<<N_NODES / 64, 256, 0, stream>>>(h, wb, z12a);

    bf16* zc = z12a;
    bf16* zn = z12b;
    for (int l = 0; l < DEPTH; ++l) {
        const bf16* wbn = (l + 1 < DEPTH) ? (wb + (size_t)(l + 1) * 32768) : nullptr;
        fused_layer<<<N_NODES / 64, 512, 0, stream>>>(
            h, zc, src, code, rand_edge,
            Tb + (size_t)l * 8192,
            pre_W + (size_t)l * 384 * 128 + 368 * 128,   // Wr: rand-edge rows of pretrans W
            wc + (size_t)l * 81920,
            post_b + l * HID,
            wbn, zn);
        bf16* t = zc; zc = zn; zn = t;
    }

    readout<<<N_GRAPHS, 128, 0, stream>>>(h, ro_W1, ro_b1, ro_W2, ro_b2, (float*)d_out);
}